// Round 6
// baseline (40.903 us; speedup 1.0000x reference)
//
#include <hip/hip_runtime.h>
#include <hip/hip_bf16.h>

#define NN 2048   // n_nodes
#define CC 512    // channels

typedef __bf16 bf16x8 __attribute__((ext_vector_type(8)));
typedef float  f32x4  __attribute__((ext_vector_type(4)));
typedef int    i32x4  __attribute__((ext_vector_type(4)));
typedef unsigned short u16x4 __attribute__((ext_vector_type(4)));

#define GLD_LDS16(gptr, lptr)                                                        \
    __builtin_amdgcn_global_load_lds(                                                \
        (const __attribute__((address_space(1))) void*)(gptr),                       \
        (__attribute__((address_space(3))) void*)(lptr), 16, 0, 0)

__device__ __forceinline__ unsigned short f2bf(float f) {
    unsigned int u = __builtin_bit_cast(unsigned int, f);
    u += 0x7FFFu + ((u >> 16) & 1u);
    return (unsigned short)(u >> 16);
}
__device__ __forceinline__ float bf2f(unsigned short u) {
    unsigned int v = (unsigned int)u << 16;
    return __builtin_bit_cast(float, v);
}

// ---- fused prep:
//   blocks [0,4096): cast L->bf16, XCD-ALIGNED so writer XCD == consumer XCD
//     (GEMM XCD k reads B rows [256k, 256k+256)). L f32 read is non-temporal
//     (streaming; don't evict Lbf). Lbf stored normally -> local-L2 dirty hit.
//   blocks [4096,4352): x [2048][512] -> xT f32 [512][2048] + vT bf16. These are
//     consumed by ALL XCDs -> non-temporal store (L3-clean, no remote-dirty probes).
__global__ void prep_kernel(const float* __restrict__ L,
                            unsigned short* __restrict__ Lbf,
                            const float* __restrict__ x,
                            unsigned short* __restrict__ vbf,
                            float* __restrict__ xT) {
    __shared__ float tile[64][65];
    if (blockIdx.x < 4096) {
        int xcd = blockIdx.x & 7;
        int j   = blockIdx.x >> 3;               // 0..511
        int row = xcd * 256 + (j >> 1);          // rows this XCD's GEMM blocks consume
        size_t off = (size_t)row * NN + (j & 1) * 1024 + threadIdx.x * 4;
        f32x4 v = __builtin_nontemporal_load((const f32x4*)(L + off));
        u16x4 o;
        o[0] = f2bf(v[0]); o[1] = f2bf(v[1]); o[2] = f2bf(v[2]); o[3] = f2bf(v[3]);
        *(u16x4*)(Lbf + off) = o;
    } else {
        int b2 = blockIdx.x - 4096;
        int bi = b2 & 31;    // node tile
        int bc = b2 >> 5;    // channel tile
        int tid = threadIdx.x;
        #pragma unroll
        for (int rr = 0; rr < 16; ++rr) {
            int r = (tid >> 6) + rr * 4;
            int c = tid & 63;
            tile[r][c] = x[(size_t)(bi * 64 + r) * CC + bc * 64 + c];
        }
        __syncthreads();
        #pragma unroll
        for (int rr = 0; rr < 16; ++rr) {
            int cc2 = (tid >> 6) + rr * 4;
            int r   = tid & 63;
            float v = tile[r][cc2];
            size_t addr = (size_t)(bc * 64 + cc2) * NN + bi * 64 + r;
            __builtin_nontemporal_store(v, xT + addr);
            __builtin_nontemporal_store(f2bf(v), vbf + addr);
        }
    }
}

// ---- GEMM w = v @ L (L symmetric -> both operands row-read), 64x64 tile,
//      8 waves each owning a disjoint K-chunk of 256 (8 sub-tiles of BK=32),
//      per-wave private LDS double-buffer + global_load_lds, counted vmcnt,
//      ZERO barriers in main loop; cross-wave reduction through LDS.
//      PHASE 1: vout = bf16(w)                          (w = xT*L, raw; nt store)
//      PHASE 2: out[n][c] = c0*xT + c1t*w1 + c2t^2*w2   (LDS-staged coalesced) ----
template <int PHASE>
__global__ __launch_bounds__(512)
void gemm_step_kernel(const unsigned short* __restrict__ A,   // [512][2048] bf16 (phase2: also w1)
                      const unsigned short* __restrict__ Lb,  // [2048][2048] bf16
                      const float* __restrict__ xT,           // [512][2048] f32 (phase2)
                      unsigned short* __restrict__ vout,      // [512][2048] bf16 (phase1)
                      float* __restrict__ out,                // [2048][512] f32 (phase2)
                      const float* __restrict__ tptr) {
    __shared__ short lds[65536];   // 128 KB: 8 waves x 2 bufs x (A 4KB + B 4KB)

    const int tid  = threadIdx.x;
    const int lane = tid & 63;
    const int wid  = tid >> 6;          // 0..7

    // XCD swizzle (grid 256 = 8 m-tiles x 32 n-tiles)
    const int bid = blockIdx.x;
    const int xcd = bid & 7, idx = bid >> 3;
    const int n0  = (xcd * 4 + (idx & 3)) * 64;   // node dim
    const int m0  = (idx >> 2) * 64;              // channel dim

    short* wbase = lds + wid * 8192;    // this wave's 16KB
    const int kw = wid * 256;           // this wave's K-chunk base

    // staging source pointers: instr i covers granules g = i*64 + lane:
    // row = g>>2, slot = g&3, stored kb = (slot - (row>>1)) & 3
    const unsigned short* pA[4];
    const unsigned short* pB[4];
    #pragma unroll
    for (int i = 0; i < 4; ++i) {
        int row = i * 16 + (lane >> 2);
        int kb  = ((lane & 3) - (row >> 1)) & 3;
        pA[i] = A  + (size_t)(m0 + row) * NN + kw + kb * 8;
        pB[i] = Lb + (size_t)(n0 + row) * NN + kw + kb * 8;
    }

    auto issue = [&](int kt, int buf) {   // 8 loads (A 4 + B 4)
        short* d = wbase + buf * 4096;
        #pragma unroll
        for (int i = 0; i < 4; ++i) {
            GLD_LDS16(pA[i] + kt * 32, d + i * 512);
            GLD_LDS16(pB[i] + kt * 32, d + 2048 + i * 512);
        }
    };

    f32x4 acc[4][4] = {};

    issue(0, 0);
    issue(1, 1);

    #pragma unroll
    for (int i = 0; i < 8; ++i) {
        if (i < 7) asm volatile("s_waitcnt vmcnt(8)" ::: "memory");
        else       asm volatile("s_waitcnt vmcnt(0)" ::: "memory");

        const short* sb = wbase + (i & 1) * 4096;
        bf16x8 af[4], bfr[4];
        #pragma unroll
        for (int f = 0; f < 4; ++f) {
            int row  = f * 16 + (lane & 15);
            int slot = ((lane >> 4) + (row >> 1)) & 3;
            int g    = row * 4 + slot;
            af[f]  = __builtin_bit_cast(bf16x8, *(const i32x4*)(sb + g * 8));
            bfr[f] = __builtin_bit_cast(bf16x8, *(const i32x4*)(sb + 2048 + g * 8));
        }
        // fragments must be in VGPRs before re-staging this buffer
        asm volatile("s_waitcnt lgkmcnt(0)" ::: "memory");
        if (i < 6) issue(i + 2, i & 1);

        __builtin_amdgcn_s_setprio(1);
        #pragma unroll
        for (int fm = 0; fm < 4; ++fm)
            #pragma unroll
            for (int fn = 0; fn < 4; ++fn)
                acc[fm][fn] = __builtin_amdgcn_mfma_f32_16x16x32_bf16(
                    af[fm], bfr[fn], acc[fm][fn], 0, 0, 0);
        __builtin_amdgcn_s_setprio(0);
    }

    // ---- cross-wave reduction: stash partials in (reused) LDS ----
    float* scr = (float*)lds;
    #pragma unroll
    for (int fm = 0; fm < 4; ++fm)
        #pragma unroll
        for (int fn = 0; fn < 4; ++fn)
            *(f32x4*)(scr + wid * 4096 + (fm * 4 + fn) * 256 + lane * 4) = acc[fm][fn];
    __syncthreads();

    // wave W reduces fragment-chunks j = W and j = W+8 across all 8 partials
    f32x4 ss[2] = {};
    #pragma unroll
    for (int h = 0; h < 2; ++h)
        #pragma unroll
        for (int w = 0; w < 8; ++w)
            ss[h] += *(const f32x4*)(scr + w * 4096 + (wid + h * 8) * 256 + lane * 4);

    if (PHASE == 1) {
        #pragma unroll
        for (int h = 0; h < 2; ++h) {
            int j  = wid + h * 8;
            int fm = j >> 2, fn = j & 3;
            int mb = m0 + fm * 16 + ((lane >> 4) << 2);
            int n  = n0 + fn * 16 + (lane & 15);
            #pragma unroll
            for (int r = 0; r < 4; ++r)
                __builtin_nontemporal_store(f2bf(ss[h][r]),
                                            vout + (size_t)(mb + r) * NN + n);
        }
    } else {
        // degree-2 Chebyshev-node interpolation of exp(-s) on [0, 0.42*t]
        float tt = fmaxf(tptr[0], 1e-8f);
        float T  = 0.42f * tt;
        float c0, c1, c2;
        if (T < 1e-3f) { c0 = 1.0f; c1 = -1.0f; c2 = 0.5f; }
        else {
            float sa = T * 0.9330127f, sm = T * 0.5f, sc = T * 0.0669873f;
            float fa = __expf(-sa), fm_ = __expf(-sm), fc = __expf(-sc);
            float d01  = (fa - fm_) / (sa - sm);
            float d12  = (fm_ - fc) / (sm - sc);
            float d012 = (d01 - d12) / (sa - sc);
            c2 = d012;
            c1 = d01 - d012 * (sa + sm);
            c0 = fa - d01 * sa + d012 * sa * sm;
        }
        const float C1 = c1 * tt;
        const float C2 = c2 * tt * tt;

        // stage output tile in LDS (pad 68 -> 16B-aligned rows), coalesced write
        float (*ot)[68] = (float (*)[68])lds;   // 64*68*4 = 17.4 KB
        __syncthreads();                        // all reduction reads of scr done
        #pragma unroll
        for (int h = 0; h < 2; ++h) {
            int j   = wid + h * 8;
            int fm  = j >> 2, fn = j & 3;
            int m_l = fm * 16 + ((lane >> 4) << 2);
            int n_l = fn * 16 + (lane & 15);
            size_t abase = (size_t)(m0 + m_l) * NN + (n0 + n_l);
            #pragma unroll
            for (int r = 0; r < 4; ++r) {
                size_t a = abase + (size_t)r * NN;
                ot[n_l][m_l + r] = c0 * xT[a] + C1 * bf2f(A[a]) + C2 * ss[h][r];
            }
        }
        __syncthreads();
        #pragma unroll
        for (int rr = 0; rr < 2; ++rr) {
            int e    = rr * 512 + tid;          // 1024 f32x4 = 4096 floats
            int nloc = e >> 4, mq = e & 15;
            f32x4 v  = *(const f32x4*)&ot[nloc][mq * 4];
            *(f32x4*)(out + (size_t)(n0 + nloc) * CC + m0 + mq * 4) = v;
        }
    }
}

extern "C" void kernel_launch(void* const* d_in, const int* in_sizes, int n_in,
                              void* d_out, int out_size, void* d_ws, size_t ws_size,
                              hipStream_t stream) {
    (void)in_sizes; (void)n_in; (void)out_size; (void)ws_size;
    const float* x = (const float*)d_in[0];
    const float* L = (const float*)d_in[1];
    const float* t = (const float*)d_in[2];
    float* out = (float*)d_out;

    char* ws = (char*)d_ws;
    unsigned short* Lbf  = (unsigned short*)ws;                   // 8 MB
    unsigned short* vA   = (unsigned short*)(ws + (8  << 20));    // 2 MB  bf16(xT)
    unsigned short* w1bf = (unsigned short*)(ws + (10 << 20));    // 2 MB  bf16(xT*L)
    float*          xT   = (float*)        (ws + (12 << 20));     // 4 MB  f32 xT

    prep_kernel<<<4096 + 256, 256, 0, stream>>>(L, Lbf, x, vA, xT);
    gemm_step_kernel<1><<<256, 512, 0, stream>>>(vA,   Lbf, nullptr, w1bf, nullptr, t);
    gemm_step_kernel<2><<<256, 512, 0, stream>>>(w1bf, Lbf, xT,      nullptr, out,  t);
}